// Round 11
// baseline (613.306 us; speedup 1.0000x reference)
//
#include <hip/hip_runtime.h>
#include <hip/hip_bf16.h>
#include <math.h>

#define B_      256
#define DA      1024
#define S_      8
#define DK      128
#define NKEYS   100000
#define KMAX    32
#define KTOT    1024            // S_*DK flattened reduction dim
#define BN      128             // n-tile per block (pass_b)
#define BK      64              // k per LDS step; LDS row = 128 B
#define NBLK    ((NKEYS + BN - 1) / BN)

typedef __attribute__((ext_vector_type(8))) short short8;
typedef __attribute__((ext_vector_type(4))) float f32x4;

typedef const __attribute__((address_space(1))) unsigned gu32;
typedef __attribute__((address_space(3))) unsigned lu32;
#define GLOAD_LDS16(g, s) __builtin_amdgcn_global_load_lds((gu32*)(g), (lu32*)(s), 16, 0, 0)

__device__ __forceinline__ float bf16_up(short h) {
    union { unsigned u; float f; } cv;
    cv.u = ((unsigned)(unsigned short)h) << 16;
    return cv.f;
}

// ---------------------------------------------------------------------------
// Pass A: queries = einsum('ska,ba->bsk', W_Q, z), L2-normalized (fp64 acc).
// (unchanged -- QT/Qb bit-identical across rounds)
// ---------------------------------------------------------------------------
__global__ __launch_bounds__(128) void pass_a_kernel(
    const float* __restrict__ z, const float* __restrict__ wq,
    float* __restrict__ QT, __hip_bfloat16* __restrict__ Qb)
{
    const int b = blockIdx.x;
    const int s = blockIdx.y;
    __shared__ float zsh[DA];
    for (int i = threadIdx.x; i < DA; i += 128) zsh[i] = z[b * DA + i];
    __syncthreads();
    const int k = threadIdx.x;
    const float* wrow = wq + (size_t)(s * DK + k) * DA;
    double acc = 0.0;
    #pragma unroll 4
    for (int a = 0; a < DA; a += 4) {
        const float4 w4 = *reinterpret_cast<const float4*>(wrow + a);
        acc += (double)w4.x * (double)zsh[a + 0];
        acc += (double)w4.y * (double)zsh[a + 1];
        acc += (double)w4.z * (double)zsh[a + 2];
        acc += (double)w4.w * (double)zsh[a + 3];
    }
    double sq = acc * acc;
    #pragma unroll
    for (int off = 32; off > 0; off >>= 1) sq += __shfl_down(sq, off);
    __shared__ double part[2];
    if ((threadIdx.x & 63) == 0) part[threadIdx.x >> 6] = sq;
    __syncthreads();
    const double ss  = part[0] + part[1];
    const double inv = 1.0 / (sqrt(ss) + 1e-8);
    const float qv = (float)(acc * inv);
    QT[(size_t)(s * DK + k) * B_ + b] = qv;
    Qb[(size_t)b * KTOT + s * DK + k] = __float2bfloat16(qv);
}

// ---------------------------------------------------------------------------
// Pass K: F + Kb = bf16(key * f). (verbatim R6 -- best measured)
// ---------------------------------------------------------------------------
__global__ __launch_bounds__(256) void pass_k_kernel(
    const float* __restrict__ keys, const float* __restrict__ aw,
    float* __restrict__ F, __hip_bfloat16* __restrict__ Kb)
{
    float e[S_];
    float mx = aw[0];
    #pragma unroll
    for (int i = 1; i < S_; ++i) mx = fmaxf(mx, aw[i]);
    float se = 0.f;
    #pragma unroll
    for (int i = 0; i < S_; ++i) { e[i] = expf(aw[i] - mx); se += e[i]; }

    const int g = threadIdx.x >> 4, l = threadIdx.x & 15;
    const long long sn = (long long)blockIdx.x * 16 + g;
    const float* row = keys + (size_t)sn * DK + l * 8;
    const float4 r0 = *reinterpret_cast<const float4*>(row + 0);
    const float4 r1 = *reinterpret_cast<const float4*>(row + 4);
    double sq = (double)r0.x * r0.x + (double)r0.y * r0.y +
                (double)r0.z * r0.z + (double)r0.w * r0.w +
                (double)r1.x * r1.x + (double)r1.y * r1.y +
                (double)r1.z * r1.z + (double)r1.w * r1.w;
    #pragma unroll
    for (int off = 1; off < 16; off <<= 1) sq += __shfl_xor(sq, off);
    const int s = (int)(sn / NKEYS);
    const float w = e[s] / se;
    const float f = (float)((double)w / (sqrt(sq) + 1e-8));
    if (l == 0) F[sn] = f;

    const float vv[8] = {r0.x, r0.y, r0.z, r0.w, r1.x, r1.y, r1.z, r1.w};
    short8 pk;
    #pragma unroll
    for (int ee = 0; ee < 8; ++ee) {
        __hip_bfloat16 h = __float2bfloat16(vv[ee] * f);
        pk[ee] = *reinterpret_cast<short*>(&h);
    }
    *reinterpret_cast<short8*>((__hip_bfloat16*)Kb + (size_t)sn * DK + l * 8) = pk;
}

// ---------------------------------------------------------------------------
// Pass B: verbatim R6 structure (tile 256b x 128n, 512 thr / 8 waves,
// A single-buffered 32KB gload_lds, B double-buffered 2x16KB with counted
// vmcnt(2)) + per-row stats epilogue (SM/SQ atomics, verified in R10).
// ---------------------------------------------------------------------------
__global__ __launch_bounds__(512) void pass_b_kernel(
    const __hip_bfloat16* __restrict__ Kb, const __hip_bfloat16* __restrict__ Qb,
    __hip_bfloat16* __restrict__ C,
    float* __restrict__ SM, float* __restrict__ SQ)
{
    __shared__ __align__(16) char smem[65536];   // A:[0,32K)  B0:[32K,48K) B1:[48K,64K)
    const int n0 = blockIdx.x * BN;
    const int tid = threadIdx.x;
    const int w = tid >> 6, l = tid & 63;
    const int ln = l & 15, lk = l >> 4;
    const int wm = w >> 1, wn = w & 1;           // 4M x 2N wave grid
    const int sl = l & 7, lr = l >> 3;           // staging slot / row

    f32x4 acc[4][4];
    #pragma unroll
    for (int i = 0; i < 4; ++i)
        #pragma unroll
        for (int j = 0; j < 4; ++j) acc[i][j] = (f32x4){0.f, 0.f, 0.f, 0.f};

    const char* qb = (const char*)Qb;
    const char* kb = (const char*)Kb;

    auto stage_b = [&](int t) {
        const int kc   = t * BK;                 // may be KTOT on last prefetch (slack-guarded)
        const int sidx = kc >> 7;
        const int kl   = kc & (DK - 1);
        #pragma unroll
        for (int i = 0; i < 2; ++i) {
            const int j  = w + 8 * i;            // chunk 0..15
            const int nr = j * 8 + lr;           // tile row 0..127
            const size_t gn = (size_t)sidx * NKEYS + (n0 + nr);
            const char* g = kb + (gn * DK + kl + ((sl ^ (nr & 7)) << 3)) * 2;
            GLOAD_LDS16(g, smem + 32768 + (t & 1) * 16384 + j * 1024);
        }
    };

    stage_b(0);

    for (int t = 0; t < 16; ++t) {
        const int kc = t * BK;
        #pragma unroll
        for (int i = 0; i < 4; ++i) {
            const int j  = w + 8 * i;            // chunk 0..31
            const int bq = j * 8 + lr;           // query row 0..255
            const char* g = qb + ((size_t)bq * KTOT + kc + ((sl ^ (bq & 7)) << 3)) * 2;
            GLOAD_LDS16(g, smem + j * 1024);
        }
        stage_b(t + 1);
        asm volatile("s_waitcnt vmcnt(2)" ::: "memory");
        __builtin_amdgcn_sched_barrier(0);
        __builtin_amdgcn_s_barrier();
        __builtin_amdgcn_sched_barrier(0);
        const char* bbase = smem + 32768 + (t & 1) * 16384;
        #pragma unroll
        for (int kw = 0; kw < 2; ++kw) {
            const int slot = kw * 4 + lk;
            short8 af[4], bf[4];
            #pragma unroll
            for (int mi = 0; mi < 4; ++mi) {
                const int bq = wm * 64 + mi * 16 + ln;
                af[mi] = *reinterpret_cast<const short8*>(smem + bq * 128 + ((slot ^ (bq & 7)) << 4));
            }
            #pragma unroll
            for (int nf = 0; nf < 4; ++nf) {
                const int nr = wn * 64 + nf * 16 + ln;
                bf[nf] = *reinterpret_cast<const short8*>(bbase + nr * 128 + ((slot ^ (nr & 7)) << 4));
            }
            #pragma unroll
            for (int mi = 0; mi < 4; ++mi)
                #pragma unroll
                for (int nf = 0; nf < 4; ++nf)
                    acc[mi][nf] = __builtin_amdgcn_mfma_f32_16x16x32_bf16(
                        af[mi], bf[nf], acc[mi][nf], 0, 0, 0);
        }
        __builtin_amdgcn_s_barrier();
    }
    // ---- C store + per-row stats (row=(lane>>4)*4+reg, col=lane&15) ----
    #pragma unroll
    for (int mi = 0; mi < 4; ++mi) {
        #pragma unroll
        for (int r = 0; r < 4; ++r) {
            const int bq = wm * 64 + mi * 16 + lk * 4 + r;
            float s_ = 0.f, q_ = 0.f;
            #pragma unroll
            for (int nf = 0; nf < 4; ++nf) {
                const int n = n0 + wn * 64 + nf * 16 + ln;
                if (n < NKEYS) {
                    const float v = acc[mi][nf][r];
                    C[(size_t)bq * NKEYS + n] = __float2bfloat16(v);
                    s_ += v; q_ += v * v;
                }
            }
            #pragma unroll
            for (int off = 1; off < 16; off <<= 1) {
                s_ += __shfl_xor(s_, off);
                q_ += __shfl_xor(q_, off);
            }
            if (ln == 0) {
                atomicAdd(&SM[bq], s_);
                atomicAdd(&SQ[bq], q_);
            }
        }
    }
}

// ---------------------------------------------------------------------------
// Pass C v4: NO histogram. thr = mu + 2.8*sigma analytically (E[#cands]=255;
// exact-32nd at ~mu+3.4sigma, gap 0.61sigma >> coarse bf16 error 4e-3, so the
// true top-32 always survives compaction). Count-checked fallback ladder
// (2.0s -> mu -> -1.1) makes it airtight. One stream + fp64 exact re-rank +
// exact top-32 (frozen) -> output bit-identical.
// ---------------------------------------------------------------------------
#define MAXC 2048
#define NV8 12500               // short8's per row (100000/8)
#define CTH 1024                // threads

__global__ __launch_bounds__(1024) void pass_c_kernel(
    const __hip_bfloat16* __restrict__ C, const float* __restrict__ keys,
    const float* __restrict__ QT, const float* __restrict__ F,
    const float* __restrict__ SM, const float* __restrict__ SQ,
    const float* __restrict__ tau_p, const float* __restrict__ lam_p,
    const unsigned char* __restrict__ warm_p, float* __restrict__ out)
{
    const int b = blockIdx.x, tid = threadIdx.x;
    __shared__ double cval[MAXC];
    __shared__ int cidx[MAXC];
    __shared__ int cnt;
    __shared__ float sh_stat[2];
    __shared__ double topv[KMAX];
    __shared__ int topi[KMAX];

    const __hip_bfloat16* crow = C + (size_t)b * NKEYS;

    if (tid == 0) {
        const float S1 = SM[b], S2 = SQ[b];
        const float mu = S1 / NKEYS;
        sh_stat[0] = mu;
        sh_stat[1] = sqrtf(fmaxf(S2 / NKEYS - mu * mu, 1e-12f));
    }
    __syncthreads();
    const float mu = sh_stat[0], sg = sh_stat[1];

    // ---- compact candidates: analytic threshold + fallback ladder ----
    int m = 0;
    #pragma unroll 1
    for (int attempt = 0; attempt < 4; ++attempt) {
        const float ct = (attempt == 0) ? (mu + 2.8f * sg)
                       : (attempt == 1) ? (mu + 2.0f * sg)
                       : (attempt == 2) ? mu : -1.1f;
        __syncthreads();
        if (tid == 0) cnt = 0;
        __syncthreads();
        for (int i = tid; i < NV8; i += CTH) {
            const short8 v8 = *reinterpret_cast<const short8*>(crow + i * 8);
            #pragma unroll
            for (int e = 0; e < 8; ++e) {
                if (bf16_up(v8[e]) >= ct) {
                    const int p = atomicAdd(&cnt, 1);
                    if (p < MAXC) cidx[p] = i * 8 + e;
                }
            }
        }
        __syncthreads();
        m = min(cnt, MAXC);
        if (m >= KMAX) break;
    }

    // ---- fp64 exact re-rank, one candidate per wave (16 waves) ----
    const int wave = tid >> 6, lane = tid & 63;
    const int si = lane >> 3, kg = lane & 7;
    for (int c = wave; c < m; c += 16) {
        const int n = cidx[c];
        const float f = F[(size_t)si * NKEYS + n];
        const float* krow = keys + ((size_t)si * NKEYS + n) * DK + kg * 16;
        const float4 k0 = *reinterpret_cast<const float4*>(krow + 0);
        const float4 k1 = *reinterpret_cast<const float4*>(krow + 4);
        const float4 k2 = *reinterpret_cast<const float4*>(krow + 8);
        const float4 k3 = *reinterpret_cast<const float4*>(krow + 12);
        const float kf[16] = {k0.x, k0.y, k0.z, k0.w, k1.x, k1.y, k1.z, k1.w,
                              k2.x, k2.y, k2.z, k2.w, k3.x, k3.y, k3.z, k3.w};
        double acc = 0.0;
        #pragma unroll
        for (int j = 0; j < 16; ++j) {
            const float q = QT[(size_t)(si * DK + kg * 16 + j) * B_ + b];
            acc += (double)q * ((double)kf[j] * (double)f);
        }
        #pragma unroll
        for (int off = 1; off < 64; off <<= 1) acc += __shfl_xor(acc, off);
        if (lane == 0) cval[c] = acc;
    }
    __syncthreads();

    // ---- single-wave exact top-32 (desc value, ties -> asc index) ----
    if (tid < 64) {
        for (int r = 0; r < KMAX; ++r) {
            double bv = -1e300; int bi = 0x7fffffff; int bp = -1;
            for (int c = tid; c < m; c += 64) {
                const double v = cval[c]; const int ix = cidx[c];
                if (v > bv || (v == bv && ix < bi)) { bv = v; bi = ix; bp = c; }
            }
            #pragma unroll
            for (int off = 32; off > 0; off >>= 1) {
                const double ov = __shfl_xor(bv, off);
                const int oi = __shfl_xor(bi, off);
                const int op = __shfl_xor(bp, off);
                if (ov > bv || (ov == bv && oi < bi)) { bv = ov; bi = oi; bp = op; }
            }
            if (tid == 0) { topv[r] = bv; topi[r] = bi; if (bp >= 0) cval[bp] = -1e301; }
        }
        if (tid == 0) {
            const float lamv = lam_p[0];
            const float tauv = tau_p[0];
            const bool warm = warm_p[0] != 0;
            float al[KMAX];
            float ssum = 0.f;
            if (warm) {
                const float x0 = (float)topv[0] / 0.1f;
                for (int i = 0; i < KMAX; ++i) {
                    const float e = expf((float)topv[i] / 0.1f - x0);
                    al[i] = e; ssum += e;
                }
            } else {
                for (int i = 0; i < KMAX; ++i) {
                    const float v = (float)topv[i];
                    const float g = 1.0f / (1.0f + expf(-(lamv * (v - tauv))));
                    const float rr = g * expf(v / 0.1f);
                    al[i] = rr; ssum += rr;
                }
            }
            for (int i = 0; i < KMAX; ++i) {
                out[b * KMAX + i] = al[i] / ssum;
                out[B_ * KMAX + b * KMAX + i] = (float)topi[i];
            }
        }
    }
}

// ---------------------------------------------------------------------------
extern "C" void kernel_launch(void* const* d_in, const int* in_sizes, int n_in,
                              void* d_out, int out_size, void* d_ws, size_t ws_size,
                              hipStream_t stream) {
    const float* z    = (const float*)d_in[0];
    const float* keys = (const float*)d_in[1];
    const float* wq   = (const float*)d_in[2];
    const float* aw   = (const float*)d_in[3];
    const float* tau  = (const float*)d_in[4];
    const float* lam  = (const float*)d_in[5];
    const unsigned char* warm = (const unsigned char*)d_in[6];
    float* out = (float*)d_out;

    char* ws = (char*)d_ws;
    float* QT           = (float*)ws;                          // @0       1.0 MB
    float* F            = (float*)(ws + (1 << 20));            // @1MB     3.2 MB
    float* SM           = (float*)(ws + (6 << 20));            // @6MB     1 KB
    float* SQ           = SM + B_;                             //          1 KB
    __hip_bfloat16* Qb  = (__hip_bfloat16*)(ws + (8 << 20));   // @8MB     0.5 MB
    __hip_bfloat16* Kb  = (__hip_bfloat16*)(ws + (16 << 20));  // @16MB  204.8 MB
    __hip_bfloat16* C   = (__hip_bfloat16*)(ws + ((size_t)232 << 20)); // @232MB 51.2 MB (slack absorbs OOB/prefetch Kb reads)

    hipMemsetAsync(SM, 0, 2 * B_ * sizeof(float), stream);     // zero stats each call

    pass_a_kernel<<<dim3(B_, S_), 128, 0, stream>>>(z, wq, QT, Qb);
    pass_k_kernel<<<dim3((S_ * NKEYS) / 16), 256, 0, stream>>>(keys, aw, F, Kb);
    pass_b_kernel<<<dim3(NBLK), 512, 0, stream>>>(Kb, Qb, C, SM, SQ);
    pass_c_kernel<<<dim3(B_), 1024, 0, stream>>>(C, keys, QT, F, SM, SQ, tau, lam, warm, out);
}

// Round 12
// 427.473 us; speedup vs baseline: 1.4347x; 1.4347x over previous
//
#include <hip/hip_runtime.h>
#include <hip/hip_bf16.h>
#include <math.h>

#define B_      256
#define DA      1024
#define S_      8
#define DK      128
#define NKEYS   100000
#define KMAX    32
#define KTOT    1024            // S_*DK flattened reduction dim
#define BN      128             // n-tile per block (pass_b)
#define BK      64              // k per LDS step; LDS row = 128 B
#define NBLK    ((NKEYS + BN - 1) / BN)

typedef __attribute__((ext_vector_type(8))) short short8;
typedef __attribute__((ext_vector_type(4))) float f32x4;

typedef const __attribute__((address_space(1))) unsigned gu32;
typedef __attribute__((address_space(3))) unsigned lu32;
#define GLOAD_LDS16(g, s) __builtin_amdgcn_global_load_lds((gu32*)(g), (lu32*)(s), 16, 0, 0)

__device__ __forceinline__ float bf16_up(short h) {
    union { unsigned u; float f; } cv;
    cv.u = ((unsigned)(unsigned short)h) << 16;
    return cv.f;
}

// ---------------------------------------------------------------------------
// Pass A: queries = einsum('ska,ba->bsk', W_Q, z), L2-normalized (fp64 acc).
// (unchanged -- QT/Qb bit-identical across rounds)
// ---------------------------------------------------------------------------
__global__ __launch_bounds__(128) void pass_a_kernel(
    const float* __restrict__ z, const float* __restrict__ wq,
    float* __restrict__ QT, __hip_bfloat16* __restrict__ Qb)
{
    const int b = blockIdx.x;
    const int s = blockIdx.y;
    __shared__ float zsh[DA];
    for (int i = threadIdx.x; i < DA; i += 128) zsh[i] = z[b * DA + i];
    __syncthreads();
    const int k = threadIdx.x;
    const float* wrow = wq + (size_t)(s * DK + k) * DA;
    double acc = 0.0;
    #pragma unroll 4
    for (int a = 0; a < DA; a += 4) {
        const float4 w4 = *reinterpret_cast<const float4*>(wrow + a);
        acc += (double)w4.x * (double)zsh[a + 0];
        acc += (double)w4.y * (double)zsh[a + 1];
        acc += (double)w4.z * (double)zsh[a + 2];
        acc += (double)w4.w * (double)zsh[a + 3];
    }
    double sq = acc * acc;
    #pragma unroll
    for (int off = 32; off > 0; off >>= 1) sq += __shfl_down(sq, off);
    __shared__ double part[2];
    if ((threadIdx.x & 63) == 0) part[threadIdx.x >> 6] = sq;
    __syncthreads();
    const double ss  = part[0] + part[1];
    const double inv = 1.0 / (sqrt(ss) + 1e-8);
    const float qv = (float)(acc * inv);
    QT[(size_t)(s * DK + k) * B_ + b] = qv;
    Qb[(size_t)b * KTOT + s * DK + k] = __float2bfloat16(qv);
}

// ---------------------------------------------------------------------------
// Pass K: F + Kb = bf16(key * f). (verbatim R6)
// ---------------------------------------------------------------------------
__global__ __launch_bounds__(256) void pass_k_kernel(
    const float* __restrict__ keys, const float* __restrict__ aw,
    float* __restrict__ F, __hip_bfloat16* __restrict__ Kb)
{
    float e[S_];
    float mx = aw[0];
    #pragma unroll
    for (int i = 1; i < S_; ++i) mx = fmaxf(mx, aw[i]);
    float se = 0.f;
    #pragma unroll
    for (int i = 0; i < S_; ++i) { e[i] = expf(aw[i] - mx); se += e[i]; }

    const int g = threadIdx.x >> 4, l = threadIdx.x & 15;
    const long long sn = (long long)blockIdx.x * 16 + g;
    const float* row = keys + (size_t)sn * DK + l * 8;
    const float4 r0 = *reinterpret_cast<const float4*>(row + 0);
    const float4 r1 = *reinterpret_cast<const float4*>(row + 4);
    double sq = (double)r0.x * r0.x + (double)r0.y * r0.y +
                (double)r0.z * r0.z + (double)r0.w * r0.w +
                (double)r1.x * r1.x + (double)r1.y * r1.y +
                (double)r1.z * r1.z + (double)r1.w * r1.w;
    #pragma unroll
    for (int off = 1; off < 16; off <<= 1) sq += __shfl_xor(sq, off);
    const int s = (int)(sn / NKEYS);
    const float w = e[s] / se;
    const float f = (float)((double)w / (sqrt(sq) + 1e-8));
    if (l == 0) F[sn] = f;

    const float vv[8] = {r0.x, r0.y, r0.z, r0.w, r1.x, r1.y, r1.z, r1.w};
    short8 pk;
    #pragma unroll
    for (int ee = 0; ee < 8; ++ee) {
        __hip_bfloat16 h = __float2bfloat16(vv[ee] * f);
        pk[ee] = *reinterpret_cast<short*>(&h);
    }
    *reinterpret_cast<short8*>((__hip_bfloat16*)Kb + (size_t)sn * DK + l * 8) = pk;
}

// ---------------------------------------------------------------------------
// Pass B: verbatim R6 (NO stats epilogue -- R11's 800K same-address atomics
// cost ~+100us of contention). Tile 256b x 128n, 512 thr / 8 waves, A
// single-buffered 32KB gload_lds, B double-buffered 2x16KB, counted vmcnt(2).
// ---------------------------------------------------------------------------
__global__ __launch_bounds__(512) void pass_b_kernel(
    const __hip_bfloat16* __restrict__ Kb, const __hip_bfloat16* __restrict__ Qb,
    __hip_bfloat16* __restrict__ C)
{
    __shared__ __align__(16) char smem[65536];   // A:[0,32K)  B0:[32K,48K) B1:[48K,64K)
    const int n0 = blockIdx.x * BN;
    const int tid = threadIdx.x;
    const int w = tid >> 6, l = tid & 63;
    const int ln = l & 15, lk = l >> 4;
    const int wm = w >> 1, wn = w & 1;           // 4M x 2N wave grid
    const int sl = l & 7, lr = l >> 3;           // staging slot / row

    f32x4 acc[4][4];
    #pragma unroll
    for (int i = 0; i < 4; ++i)
        #pragma unroll
        for (int j = 0; j < 4; ++j) acc[i][j] = (f32x4){0.f, 0.f, 0.f, 0.f};

    const char* qb = (const char*)Qb;
    const char* kb = (const char*)Kb;

    auto stage_b = [&](int t) {
        const int kc   = t * BK;                 // may be KTOT on last prefetch (slack-guarded)
        const int sidx = kc >> 7;
        const int kl   = kc & (DK - 1);
        #pragma unroll
        for (int i = 0; i < 2; ++i) {
            const int j  = w + 8 * i;            // chunk 0..15
            const int nr = j * 8 + lr;           // tile row 0..127
            const size_t gn = (size_t)sidx * NKEYS + (n0 + nr);
            const char* g = kb + (gn * DK + kl + ((sl ^ (nr & 7)) << 3)) * 2;
            GLOAD_LDS16(g, smem + 32768 + (t & 1) * 16384 + j * 1024);
        }
    };

    stage_b(0);

    for (int t = 0; t < 16; ++t) {
        const int kc = t * BK;
        #pragma unroll
        for (int i = 0; i < 4; ++i) {
            const int j  = w + 8 * i;            // chunk 0..31
            const int bq = j * 8 + lr;           // query row 0..255
            const char* g = qb + ((size_t)bq * KTOT + kc + ((sl ^ (bq & 7)) << 3)) * 2;
            GLOAD_LDS16(g, smem + j * 1024);
        }
        stage_b(t + 1);
        asm volatile("s_waitcnt vmcnt(2)" ::: "memory");
        __builtin_amdgcn_sched_barrier(0);
        __builtin_amdgcn_s_barrier();
        __builtin_amdgcn_sched_barrier(0);
        const char* bbase = smem + 32768 + (t & 1) * 16384;
        #pragma unroll
        for (int kw = 0; kw < 2; ++kw) {
            const int slot = kw * 4 + lk;
            short8 af[4], bf[4];
            #pragma unroll
            for (int mi = 0; mi < 4; ++mi) {
                const int bq = wm * 64 + mi * 16 + ln;
                af[mi] = *reinterpret_cast<const short8*>(smem + bq * 128 + ((slot ^ (bq & 7)) << 4));
            }
            #pragma unroll
            for (int nf = 0; nf < 4; ++nf) {
                const int nr = wn * 64 + nf * 16 + ln;
                bf[nf] = *reinterpret_cast<const short8*>(bbase + nr * 128 + ((slot ^ (nr & 7)) << 4));
            }
            #pragma unroll
            for (int mi = 0; mi < 4; ++mi)
                #pragma unroll
                for (int nf = 0; nf < 4; ++nf)
                    acc[mi][nf] = __builtin_amdgcn_mfma_f32_16x16x32_bf16(
                        af[mi], bf[nf], acc[mi][nf], 0, 0, 0);
        }
        __builtin_amdgcn_s_barrier();
    }
    #pragma unroll
    for (int mi = 0; mi < 4; ++mi) {
        #pragma unroll
        for (int nf = 0; nf < 4; ++nf) {
            const int n = n0 + wn * 64 + nf * 16 + ln;
            if (n < NKEYS) {
                #pragma unroll
                for (int r = 0; r < 4; ++r) {
                    const int bq = wm * 64 + mi * 16 + lk * 4 + r;
                    C[(size_t)bq * NKEYS + n] = __float2bfloat16(acc[mi][nf][r]);
                }
            }
        }
    }
}

// ---------------------------------------------------------------------------
// Pass C v5: own stats pass (sum/sumsq, no atomics, no histogram) ->
// analytic threshold mu+3.0*sigma (E[cands]~135; true-32nd at ~mu+3.4sigma,
// margin 0.28sigma ~ 8.7e-3 > 2x coarse-bf16 error) with count-checked
// fallback ladder (2.5s -> mu -> -1.1, airtight) -> fp64 exact re-rank ->
// single-wave exact top-32 (frozen) -> alphas.
// ---------------------------------------------------------------------------
#define MAXC 2048
#define NV8 12500               // short8's per row (100000/8)
#define CTH 1024                // threads

__global__ __launch_bounds__(1024) void pass_c_kernel(
    const __hip_bfloat16* __restrict__ C, const float* __restrict__ keys,
    const float* __restrict__ QT, const float* __restrict__ F,
    const float* __restrict__ tau_p, const float* __restrict__ lam_p,
    const unsigned char* __restrict__ warm_p, float* __restrict__ out)
{
    const int b = blockIdx.x, tid = threadIdx.x;
    __shared__ float redA[16], redB[16];
    __shared__ double cval[MAXC];
    __shared__ int cidx[MAXC];
    __shared__ int cnt;
    __shared__ float sh_stat[2];
    __shared__ double topv[KMAX];
    __shared__ int topi[KMAX];

    const __hip_bfloat16* crow = C + (size_t)b * NKEYS;

    // ---- stats: one streaming pass (sum / sumsq) ----
    float sm = 0.f, sq = 0.f;
    for (int i = tid; i < NV8; i += CTH) {
        const short8 v8 = *reinterpret_cast<const short8*>(crow + i * 8);
        #pragma unroll
        for (int e = 0; e < 8; ++e) {
            const float v = bf16_up(v8[e]);
            sm += v; sq += v * v;
        }
    }
    #pragma unroll
    for (int off = 32; off > 0; off >>= 1) {
        sm += __shfl_down(sm, off);
        sq += __shfl_down(sq, off);
    }
    if ((tid & 63) == 0) { redA[tid >> 6] = sm; redB[tid >> 6] = sq; }
    __syncthreads();
    if (tid == 0) {
        float S1 = 0.f, S2 = 0.f;
        #pragma unroll
        for (int i = 0; i < 16; ++i) { S1 += redA[i]; S2 += redB[i]; }
        const float mu = S1 / NKEYS;
        sh_stat[0] = mu;
        sh_stat[1] = sqrtf(fmaxf(S2 / NKEYS - mu * mu, 1e-12f));
    }
    __syncthreads();
    const float mu = sh_stat[0], sg = sh_stat[1];

    // ---- compact candidates: analytic threshold + fallback ladder ----
    int m = 0;
    #pragma unroll 1
    for (int attempt = 0; attempt < 4; ++attempt) {
        const float ct = (attempt == 0) ? (mu + 3.0f * sg)
                       : (attempt == 1) ? (mu + 2.5f * sg)
                       : (attempt == 2) ? mu : -1.1f;
        __syncthreads();
        if (tid == 0) cnt = 0;
        __syncthreads();
        for (int i = tid; i < NV8; i += CTH) {
            const short8 v8 = *reinterpret_cast<const short8*>(crow + i * 8);
            #pragma unroll
            for (int e = 0; e < 8; ++e) {
                if (bf16_up(v8[e]) >= ct) {
                    const int p = atomicAdd(&cnt, 1);
                    if (p < MAXC) cidx[p] = i * 8 + e;
                }
            }
        }
        __syncthreads();
        m = min(cnt, MAXC);
        if (m >= KMAX) break;
    }

    // ---- fp64 exact re-rank, one candidate per wave (16 waves) ----
    const int wave = tid >> 6, lane = tid & 63;
    const int si = lane >> 3, kg = lane & 7;
    for (int c = wave; c < m; c += 16) {
        const int n = cidx[c];
        const float f = F[(size_t)si * NKEYS + n];
        const float* krow = keys + ((size_t)si * NKEYS + n) * DK + kg * 16;
        const float4 k0 = *reinterpret_cast<const float4*>(krow + 0);
        const float4 k1 = *reinterpret_cast<const float4*>(krow + 4);
        const float4 k2 = *reinterpret_cast<const float4*>(krow + 8);
        const float4 k3 = *reinterpret_cast<const float4*>(krow + 12);
        const float kf[16] = {k0.x, k0.y, k0.z, k0.w, k1.x, k1.y, k1.z, k1.w,
                              k2.x, k2.y, k2.z, k2.w, k3.x, k3.y, k3.z, k3.w};
        double acc = 0.0;
        #pragma unroll
        for (int j = 0; j < 16; ++j) {
            const float q = QT[(size_t)(si * DK + kg * 16 + j) * B_ + b];
            acc += (double)q * ((double)kf[j] * (double)f);
        }
        #pragma unroll
        for (int off = 1; off < 64; off <<= 1) acc += __shfl_xor(acc, off);
        if (lane == 0) cval[c] = acc;
    }
    __syncthreads();

    // ---- single-wave exact top-32 (desc value, ties -> asc index) ----
    if (tid < 64) {
        for (int r = 0; r < KMAX; ++r) {
            double bv = -1e300; int bi = 0x7fffffff; int bp = -1;
            for (int c = tid; c < m; c += 64) {
                const double v = cval[c]; const int ix = cidx[c];
                if (v > bv || (v == bv && ix < bi)) { bv = v; bi = ix; bp = c; }
            }
            #pragma unroll
            for (int off = 32; off > 0; off >>= 1) {
                const double ov = __shfl_xor(bv, off);
                const int oi = __shfl_xor(bi, off);
                const int op = __shfl_xor(bp, off);
                if (ov > bv || (ov == bv && oi < bi)) { bv = ov; bi = oi; bp = op; }
            }
            if (tid == 0) { topv[r] = bv; topi[r] = bi; if (bp >= 0) cval[bp] = -1e301; }
        }
        if (tid == 0) {
            const float lamv = lam_p[0];
            const float tauv = tau_p[0];
            const bool warm = warm_p[0] != 0;
            float al[KMAX];
            float ssum = 0.f;
            if (warm) {
                const float x0 = (float)topv[0] / 0.1f;
                for (int i = 0; i < KMAX; ++i) {
                    const float e = expf((float)topv[i] / 0.1f - x0);
                    al[i] = e; ssum += e;
                }
            } else {
                for (int i = 0; i < KMAX; ++i) {
                    const float v = (float)topv[i];
                    const float g = 1.0f / (1.0f + expf(-(lamv * (v - tauv))));
                    const float rr = g * expf(v / 0.1f);
                    al[i] = rr; ssum += rr;
                }
            }
            for (int i = 0; i < KMAX; ++i) {
                out[b * KMAX + i] = al[i] / ssum;
                out[B_ * KMAX + b * KMAX + i] = (float)topi[i];
            }
        }
    }
}

// ---------------------------------------------------------------------------
extern "C" void kernel_launch(void* const* d_in, const int* in_sizes, int n_in,
                              void* d_out, int out_size, void* d_ws, size_t ws_size,
                              hipStream_t stream) {
    const float* z    = (const float*)d_in[0];
    const float* keys = (const float*)d_in[1];
    const float* wq   = (const float*)d_in[2];
    const float* aw   = (const float*)d_in[3];
    const float* tau  = (const float*)d_in[4];
    const float* lam  = (const float*)d_in[5];
    const unsigned char* warm = (const unsigned char*)d_in[6];
    float* out = (float*)d_out;

    char* ws = (char*)d_ws;
    float* QT           = (float*)ws;                          // @0       1.0 MB
    float* F            = (float*)(ws + (1 << 20));            // @1MB     3.2 MB
    __hip_bfloat16* Qb  = (__hip_bfloat16*)(ws + (8 << 20));   // @8MB     0.5 MB
    __hip_bfloat16* Kb  = (__hip_bfloat16*)(ws + (16 << 20));  // @16MB  204.8 MB
    __hip_bfloat16* C   = (__hip_bfloat16*)(ws + ((size_t)232 << 20)); // @232MB 51.2 MB (slack absorbs OOB/prefetch Kb reads)

    pass_a_kernel<<<dim3(B_, S_), 128, 0, stream>>>(z, wq, QT, Qb);
    pass_k_kernel<<<dim3((S_ * NKEYS) / 16), 256, 0, stream>>>(keys, aw, F, Kb);
    pass_b_kernel<<<dim3(NBLK), 512, 0, stream>>>(Kb, Qb, C);
    pass_c_kernel<<<dim3(B_), 1024, 0, stream>>>(C, keys, QT, F, tau, lam, warm, out);
}